// Round 7
// baseline (1350.545 us; speedup 1.0000x reference)
//
#include <hip/hip_runtime.h>
#include <hip/hip_fp16.h>
#include <stdint.h>

#define BB 256
#define TT 511
#define VV 128
#define HH 256
#define G4 1024   // 4*H

typedef _Float16 h2_t __attribute__((ext_vector_type(2)));

__device__ __forceinline__ float fdot2(uint32_t a, uint32_t b, float c) {
  return __builtin_amdgcn_fdot2(__builtin_bit_cast(h2_t, a),
                                __builtin_bit_cast(h2_t, b), c, false);
}

__device__ __forceinline__ uint32_t pack2(float a, float b) {
  __half ha = __float2half(a), hb = __float2half(b);
  return (uint32_t)__half_as_ushort(ha) | ((uint32_t)__half_as_ushort(hb) << 16);
}

// Gate-interleaved permutation: permuted col p = 4*q + m  <->  actual col q + 256*m.

// ---------------- prep kernels (all write PERMUTED layouts) ----------------

__global__ __launch_bounds__(1024) void prep_ctx_k(
    const int* __restrict__ rhythm, const int* __restrict__ meter, const int* __restrict__ keyi,
    const float* __restrict__ er, const float* __restrict__ em, const float* __restrict__ ek,
    const float* __restrict__ W, const float* __restrict__ bias, float* __restrict__ ctxW) {
  int b = blockIdx.x, p = threadIdx.x;
  int c = (p >> 2) + 256 * (p & 3);
  int r = rhythm[b], m = meter[b], k = keyi[b];
  float acc = bias[c];
#pragma unroll
  for (int e = 0; e < 16; e++) acc += er[r*16+e] * W[(0+e)*G4 + c];
#pragma unroll
  for (int e = 0; e < 16; e++) acc += em[m*16+e] * W[(16+e)*G4 + c];
#pragma unroll
  for (int e = 0; e < 16; e++) acc += ek[k*16+e] * W[(32+e)*G4 + c];
  ctxW[b*G4 + p] = acc;
}

__global__ __launch_bounds__(1024) void prep_tune_k(
    const float* __restrict__ et, const float* __restrict__ W, float* __restrict__ tuneW) {
  int v = blockIdx.x, p = threadIdx.x;
  int c = (p >> 2) + 256 * (p & 3);
  float acc = 0.f;
#pragma unroll
  for (int e = 0; e < 32; e++) acc += et[v*32+e] * W[(48+e)*G4 + c];
  tuneW[v*G4 + p] = acc;
}

__global__ __launch_bounds__(1024) void prep_U_k(
    const float* __restrict__ U, uint32_t* __restrict__ Up) {
  int kk = blockIdx.x, p = threadIdx.x;
  int c = (p >> 2) + 256 * (p & 3);
  Up[kk*G4 + p] = pack2(U[(2*kk)*G4 + c], U[(2*kk+1)*G4 + c]);
}

__global__ __launch_bounds__(128) void prep_Wd_k(
    const float* __restrict__ Wd, uint32_t* __restrict__ Wdp) {
  int kp = blockIdx.x, v = threadIdx.x;
  Wdp[kp*VV + v] = pack2(Wd[(2*kp)*VV + v], Wd[(2*kp+1)*VV + v]);
}

// ---------------- recurrent kernel ----------------
// R6 structure; ONLY change: h delivered via 1 lane-spread ds_read_b32 +
// v_readlane (SGPR operand of v_dot2) instead of 16 uniform ds_read_b128.

#define NT 512
#define KREG 48
#define KLDS 16
#define OFF_ZPART (2*KLDS*G4)
#define OFF_HBUF  (OFF_ZPART + 2*G4)
#define OFF_TLDS  (OFF_HBUF + 128)
#define SMEM_U32  (OFF_TLDS + TT + 1)
#define SMEM_BYTES (SMEM_U32*4)   // ~141.8 KB

__global__ __launch_bounds__(NT)
__attribute__((amdgpu_waves_per_eu(2, 2)))
void lstm_rec_k(
    const int* __restrict__ tune, const int* __restrict__ tlen,
    const uint32_t* __restrict__ Up, const float* __restrict__ ctxW,
    const float* __restrict__ tuneW, __half* __restrict__ h_hist) {
  extern __shared__ uint32_t smem[];
  uint32_t* Ulds  = smem;
  float*    zpart = (float*)(smem + OFF_ZPART);
  uint32_t* hbuf  = smem + OFF_HBUF;
  int*      tlds  = (int*)(smem + OFF_TLDS);

  int b    = blockIdx.x;
  int tid  = threadIdx.x;
  int g    = tid >> 8;
  int q    = tid & 255;
  int lane = tid & 63;
  int L    = tlen[b];

  for (int i = tid; i < TT; i += NT) tlds[i] = tune[b*TT + i];
  if (tid < 128) hbuf[tid] = 0u;
  for (int idx = tid; idx < 2*KLDS*G4; idx += NT) {
    int row = idx >> 10, p = idx & 1023;
    int gg = row / KLDS, r = row % KLDS;
    Ulds[idx] = Up[(gg*64 + KREG + r)*G4 + p];
  }

  uint4 ureg[KREG];
  {
    const uint32_t* ubase = Up + (size_t)(g*64)*G4 + 4*q;
#pragma unroll
    for (int kk = 0; kk < KREG; kk++) ureg[kk] = *(const uint4*)(ubase + (size_t)kk*G4);
  }
  float4 ctxv = *(const float4*)(ctxW + (size_t)b*G4 + 4*q);
  float cc = 0.f;
  __syncthreads();

  const uint32_t* uldsrow = Ulds + (size_t)(g*KLDS)*G4 + 4*q;
  bool owner = ((q >> 7) == g);
  __half* hh_base = h_hist + (size_t)b*TT*HH + q;

  for (int t = 0; t < L; t++) {
    uint32_t vh = hbuf[g*64 + lane];    // lane-spread: lane k holds h-pair k
    int v = tlds[t];
    float4 tw = *(const float4*)(tuneW + (size_t)v*G4 + 4*q);

    float a0e = 0.f, a1e = 0.f, a2e = 0.f, a3e = 0.f;
    float a0o = 0.f, a1o = 0.f, a2o = 0.f, a3o = 0.f;
#pragma unroll
    for (int kk = 0; kk < KREG; kk += 2) {
      uint32_t hs0 = (uint32_t)__builtin_amdgcn_readlane((int)vh, kk);
      uint32_t hs1 = (uint32_t)__builtin_amdgcn_readlane((int)vh, kk + 1);
      a0e = fdot2(hs0, ureg[kk].x, a0e);
      a1e = fdot2(hs0, ureg[kk].y, a1e);
      a2e = fdot2(hs0, ureg[kk].z, a2e);
      a3e = fdot2(hs0, ureg[kk].w, a3e);
      a0o = fdot2(hs1, ureg[kk+1].x, a0o);
      a1o = fdot2(hs1, ureg[kk+1].y, a1o);
      a2o = fdot2(hs1, ureg[kk+1].z, a2o);
      a3o = fdot2(hs1, ureg[kk+1].w, a3o);
    }
#pragma unroll
    for (int r = 0; r < KLDS; r += 2) {
      uint4 ua = *(const uint4*)(uldsrow + (size_t)r*G4);
      uint4 ub = *(const uint4*)(uldsrow + (size_t)(r+1)*G4);
      uint32_t hs0 = (uint32_t)__builtin_amdgcn_readlane((int)vh, KREG + r);
      uint32_t hs1 = (uint32_t)__builtin_amdgcn_readlane((int)vh, KREG + r + 1);
      a0e = fdot2(hs0, ua.x, a0e);
      a1e = fdot2(hs0, ua.y, a1e);
      a2e = fdot2(hs0, ua.z, a2e);
      a3e = fdot2(hs0, ua.w, a3e);
      a0o = fdot2(hs1, ub.x, a0o);
      a1o = fdot2(hs1, ub.y, a1o);
      a2o = fdot2(hs1, ub.z, a2o);
      a3o = fdot2(hs1, ub.w, a3o);
    }
    float s0 = a0e + a0o, s1 = a1e + a1o, s2 = a2e + a2o, s3 = a3e + a3o;
    *(float4*)(zpart + g*G4 + 4*q) = make_float4(s0, s1, s2, s3);
    __syncthreads();

    float4 zp = *(const float4*)(zpart + (1-g)*G4 + 4*q);
    float zi = s0 + zp.x + ctxv.x + tw.x;
    float zf = s1 + zp.y + ctxv.y + tw.y;
    float zg = s2 + zp.z + ctxv.z + tw.z;
    float zo = s3 + zp.w + ctxv.w + tw.w;
    float gi = 1.f / (1.f + __expf(-zi));
    float gf = 1.f / (1.f + __expf(-zf));
    float e2 = __expf(2.f*zg);
    float gg = (e2 - 1.f) / (e2 + 1.f);
    float go = 1.f / (1.f + __expf(-zo));
    cc = gf*cc + gi*gg;
    float ec = __expf(2.f*cc);
    float th = (ec - 1.f) / (ec + 1.f);
    float hv = go * th;
    if (owner) {
      __half hhv = __float2half(hv);
      ((__half*)hbuf)[q] = hhv;
      hh_base[(size_t)t*HH] = hhv;
    }
    __syncthreads();
  }
}

// ---------------- ablation probes (write to dead ws region; pure measurement) ----

#define PL_ROWS 16
#define PL_U32  (PL_ROWS*G4 + 128)
#define PL_BYTES (PL_U32*4)

__global__ __launch_bounds__(NT)
__attribute__((amdgpu_waves_per_eu(2, 2)))
void probe_lds_k(const uint32_t* __restrict__ Up, uint32_t* __restrict__ outp) {
  extern __shared__ uint32_t sm[];
  int tid = threadIdx.x, g = tid >> 8, q = tid & 255, lane = tid & 63;
  for (int i = tid; i < PL_U32; i += NT) sm[i] = Up[i & 4095] + i;
  __syncthreads();
  const uint32_t* urow = sm + 4*q;
  uint32_t* hb = sm + PL_ROWS*G4;
  uint32_t acc = 0;
  for (int t = 0; t < 128; t++) {
    uint32_t vh = hb[g*64 + lane];      // 1 lane-spread b32 (as main)
    acc ^= vh;
#pragma unroll
    for (int r = 0; r < KLDS; r++) {    // 16 spread b128 (as main)
      uint4 ua = *(const uint4*)(urow + (size_t)r*G4);
      acc ^= ua.x ^ ua.w;
    }
    __syncthreads();
    if (q == 0) hb[g*64 + (t & 63)] = acc;
    __syncthreads();
  }
  if (acc == 0xdeadbeefu) outp[tid] = acc;   // unprovable -> keeps work live
}

__global__ __launch_bounds__(NT)
__attribute__((amdgpu_waves_per_eu(2, 2)))
void probe_valu_k(const uint32_t* __restrict__ Up, float* __restrict__ outp) {
  int tid = threadIdx.x, g = tid >> 8, q = tid & 255;
  uint4 ureg[KREG];
  const uint32_t* ubase = Up + (size_t)(g*64)*G4 + 4*q;
#pragma unroll
  for (int kk = 0; kk < KREG; kk++) ureg[kk] = *(const uint4*)(ubase + (size_t)kk*G4);
  uint32_t vh = Up[tid];
  float a0e = 0.f, a1e = 0.f, a2e = 0.f, a3e = 0.f;
  float a0o = 0.f, a1o = 0.f, a2o = 0.f, a3o = 0.f;
  for (int t = 0; t < 128; t++) {
    vh ^= (uint32_t)t;                  // defeats readlane hoisting
    __syncthreads();
#pragma unroll
    for (int kk = 0; kk < KREG; kk += 2) {   // 192 fdot2 + 48 readlane
      uint32_t hs0 = (uint32_t)__builtin_amdgcn_readlane((int)vh, kk);
      uint32_t hs1 = (uint32_t)__builtin_amdgcn_readlane((int)vh, kk + 1);
      a0e = fdot2(hs0, ureg[kk].x, a0e);
      a1e = fdot2(hs0, ureg[kk].y, a1e);
      a2e = fdot2(hs0, ureg[kk].z, a2e);
      a3e = fdot2(hs0, ureg[kk].w, a3e);
      a0o = fdot2(hs1, ureg[kk+1].x, a0o);
      a1o = fdot2(hs1, ureg[kk+1].y, a1o);
      a2o = fdot2(hs1, ureg[kk+1].z, a2o);
      a3o = fdot2(hs1, ureg[kk+1].w, a3o);
    }
#pragma unroll
    for (int kk = 0; kk < 16; kk += 2) {     // +64 fdot2 + 16 readlane (reuse regs)
      uint32_t hs0 = (uint32_t)__builtin_amdgcn_readlane((int)vh, KREG + kk);
      uint32_t hs1 = (uint32_t)__builtin_amdgcn_readlane((int)vh, KREG + kk + 1);
      a0e = fdot2(hs0, ureg[kk].x, a0e);
      a1e = fdot2(hs0, ureg[kk].y, a1e);
      a2e = fdot2(hs0, ureg[kk].z, a2e);
      a3e = fdot2(hs0, ureg[kk].w, a3e);
      a0o = fdot2(hs1, ureg[kk+1].x, a0o);
      a1o = fdot2(hs1, ureg[kk+1].y, a1o);
      a2o = fdot2(hs1, ureg[kk+1].z, a2o);
      a3o = fdot2(hs1, ureg[kk+1].w, a3o);
    }
    __syncthreads();
  }
  float s = a0e + a1e + a2e + a3e + a0o + a1o + a2o + a3o;
  if (s == 1234.5678f) outp[tid] = s;        // unprovable -> keeps work live
}

// ---------------- output projection ----------------

__global__ __launch_bounds__(256) void out_gemm_k(
    const uint32_t* __restrict__ hsrc, const uint32_t* __restrict__ Wdp,
    const float* __restrict__ bd, const int* __restrict__ tlen,
    float* __restrict__ out) {
  __shared__ uint32_t A[64][128];
  int bb = blockIdx.x;
  int b  = bb >> 3, t0 = (bb & 7) << 6;
  int tid = threadIdx.x;
  int L = tlen[b];
  for (int idx = tid; idx < 64*128; idx += 256) {
    int r = idx >> 7, kp = idx & 127;
    int t = t0 + r;
    A[r][kp] = (t < TT) ? hsrc[((size_t)b*TT + t)*128 + kp] : 0u;
  }
  __syncthreads();
  int v = tid & 127, rg = tid >> 7;
  float acc[32];
#pragma unroll
  for (int r = 0; r < 32; r++) acc[r] = 0.f;
  for (int kb = 0; kb < 4; kb++) {
    uint32_t w[32];
#pragma unroll
    for (int q = 0; q < 32; q++) w[q] = Wdp[(kb*32+q)*VV + v];
#pragma unroll
    for (int r = 0; r < 32; r++) {
      const uint32_t* ar = &A[rg*32 + r][kb*32];
#pragma unroll
      for (int q4 = 0; q4 < 8; q4++) {
        uint4 a4 = *(const uint4*)(ar + q4*4);
        acc[r] = fdot2(a4.x, w[4*q4+0], acc[r]);
        acc[r] = fdot2(a4.y, w[4*q4+1], acc[r]);
        acc[r] = fdot2(a4.z, w[4*q4+2], acc[r]);
        acc[r] = fdot2(a4.w, w[4*q4+3], acc[r]);
      }
    }
  }
  float bias = bd[v];
#pragma unroll
  for (int r = 0; r < 32; r++) {
    int t = t0 + rg*32 + r;
    if (t < TT) {
      out[((size_t)b*TT + t)*VV + v] = (t < L) ? (acc[r] + bias) : bias;
    }
  }
}

// ---------------- launch ----------------

extern "C" void kernel_launch(void* const* d_in, const int* in_sizes, int n_in,
                              void* d_out, int out_size, void* d_ws, size_t ws_size,
                              hipStream_t stream) {
  const int*   tune   = (const int*)d_in[0];
  const int*   rhythm = (const int*)d_in[1];
  const int*   meter  = (const int*)d_in[2];
  const int*   keyi   = (const int*)d_in[3];
  const int*   tlen   = (const int*)d_in[4];
  const float* er     = (const float*)d_in[5];
  const float* em     = (const float*)d_in[6];
  const float* ek     = (const float*)d_in[7];
  const float* et     = (const float*)d_in[8];
  const float* W      = (const float*)d_in[9];
  const float* U      = (const float*)d_in[10];
  const float* bias   = (const float*)d_in[11];
  const float* Wd     = (const float*)d_in[12];
  const float* bd     = (const float*)d_in[13];
  (void)in_sizes; (void)n_in; (void)out_size; (void)ws_size;

  char* ws = (char*)d_ws;
  uint32_t* Up    = (uint32_t*)(ws);                                      // 512KB
  float*    ctxW  = (float*)(ws + (512<<10));                             // 1MB
  float*    tuneW = (float*)(ws + (512<<10) + (1024<<10));                // 516KB
  uint32_t* Wdp   = (uint32_t*)(ws + (512<<10) + (1024<<10) + (516<<10)); // 64KB
  float*    dead  = (float*)(ws + (512<<10));  // probe sink (ctxW, dead after rec)

  hipFuncSetAttribute((const void*)lstm_rec_k,
                      hipFuncAttributeMaxDynamicSharedMemorySize, SMEM_BYTES);
  hipFuncSetAttribute((const void*)probe_lds_k,
                      hipFuncAttributeMaxDynamicSharedMemorySize, PL_BYTES);

  prep_ctx_k <<<BB,    1024, 0, stream>>>(rhythm, meter, keyi, er, em, ek, W, bias, ctxW);
  prep_tune_k<<<VV+1,  1024, 0, stream>>>(et, W, tuneW);
  prep_U_k   <<<128,   1024, 0, stream>>>(U, Up);
  prep_Wd_k  <<<128,   VV,   0, stream>>>(Wd, Wdp);
  lstm_rec_k <<<BB, NT, SMEM_BYTES, stream>>>(tune, tlen, Up, ctxW, tuneW, (__half*)d_out);
  out_gemm_k <<<BB*8,  256,  0, stream>>>((const uint32_t*)d_out, Wdp, bd, tlen, (float*)d_out);
  probe_lds_k <<<BB, NT, PL_BYTES, stream>>>(Up, (uint32_t*)dead);
  probe_valu_k<<<BB, NT, 0,        stream>>>(Up, dead);
}

// Round 8
// 985.639 us; speedup vs baseline: 1.3702x; 1.3702x over previous
//
#include <hip/hip_runtime.h>
#include <hip/hip_fp16.h>
#include <stdint.h>

#define BB 256
#define TT 511
#define VV 128
#define HH 256
#define G4 1024   // 4*H

typedef _Float16 h2_t __attribute__((ext_vector_type(2)));

__device__ __forceinline__ float fdot2(uint32_t a, uint32_t b, float c) {
  return __builtin_amdgcn_fdot2(__builtin_bit_cast(h2_t, a),
                                __builtin_bit_cast(h2_t, b), c, false);
}

__device__ __forceinline__ uint32_t pack2(float a, float b) {
  __half ha = __float2half(a), hb = __float2half(b);
  return (uint32_t)__half_as_ushort(ha) | ((uint32_t)__half_as_ushort(hb) << 16);
}

// Gate-interleaved permutation: permuted col p = 4*q + m  <->  actual col q + 256*m.

// ---------------- prep kernels (all write PERMUTED layouts) ----------------

__global__ __launch_bounds__(1024) void prep_ctx_k(
    const int* __restrict__ rhythm, const int* __restrict__ meter, const int* __restrict__ keyi,
    const float* __restrict__ er, const float* __restrict__ em, const float* __restrict__ ek,
    const float* __restrict__ W, const float* __restrict__ bias, float* __restrict__ ctxW) {
  int b = blockIdx.x, p = threadIdx.x;
  int c = (p >> 2) + 256 * (p & 3);
  int r = rhythm[b], m = meter[b], k = keyi[b];
  float acc = bias[c];
#pragma unroll
  for (int e = 0; e < 16; e++) acc += er[r*16+e] * W[(0+e)*G4 + c];
#pragma unroll
  for (int e = 0; e < 16; e++) acc += em[m*16+e] * W[(16+e)*G4 + c];
#pragma unroll
  for (int e = 0; e < 16; e++) acc += ek[k*16+e] * W[(32+e)*G4 + c];
  ctxW[b*G4 + p] = acc;
}

__global__ __launch_bounds__(1024) void prep_tune_k(
    const float* __restrict__ et, const float* __restrict__ W, float* __restrict__ tuneW) {
  int v = blockIdx.x, p = threadIdx.x;
  int c = (p >> 2) + 256 * (p & 3);
  float acc = 0.f;
#pragma unroll
  for (int e = 0; e < 32; e++) acc += et[v*32+e] * W[(48+e)*G4 + c];
  tuneW[v*G4 + p] = acc;
}

__global__ __launch_bounds__(1024) void prep_U_k(
    const float* __restrict__ U, uint32_t* __restrict__ Up) {
  int kk = blockIdx.x, p = threadIdx.x;
  int c = (p >> 2) + 256 * (p & 3);
  Up[kk*G4 + p] = pack2(U[(2*kk)*G4 + c], U[(2*kk+1)*G4 + c]);
}

__global__ __launch_bounds__(128) void prep_Wd_k(
    const float* __restrict__ Wd, uint32_t* __restrict__ Wdp) {
  int kp = blockIdx.x, v = threadIdx.x;
  Wdp[kp*VV + v] = pack2(Wd[(2*kp)*VV + v], Wd[(2*kp+1)*VV + v]);
}

// ---------------- recurrent kernel ----------------
// R6 structure (uniform ds_read_b128 h-broadcast). ONLY change vs R6:
// the h_hist global store is DEFERRED one step (issued at the top of the
// next iteration), so neither __syncthreads()'s implicit vmcnt(0) drain
// ever waits on an un-covered store. (R1-R7 invariant ~4300cy/step was
// dominated by store-ack latency serialized at barrier 2 every step.)

#define NT 512
#define KREG 48
#define KLDS 16
#define OFF_ZPART (2*KLDS*G4)
#define OFF_HBUF  (OFF_ZPART + 2*G4)
#define OFF_TLDS  (OFF_HBUF + 128)
#define SMEM_U32  (OFF_TLDS + TT + 1)
#define SMEM_BYTES (SMEM_U32*4)   // ~141.8 KB

__global__ __launch_bounds__(NT)
__attribute__((amdgpu_waves_per_eu(2, 2)))
void lstm_rec_k(
    const int* __restrict__ tune, const int* __restrict__ tlen,
    const uint32_t* __restrict__ Up, const float* __restrict__ ctxW,
    const float* __restrict__ tuneW, __half* __restrict__ h_hist) {
  extern __shared__ uint32_t smem[];
  uint32_t* Ulds  = smem;
  float*    zpart = (float*)(smem + OFF_ZPART);
  uint32_t* hbuf  = smem + OFF_HBUF;
  int*      tlds  = (int*)(smem + OFF_TLDS);

  int b    = blockIdx.x;
  int tid  = threadIdx.x;
  int g    = tid >> 8;
  int q    = tid & 255;
  int L    = tlen[b];

  for (int i = tid; i < TT; i += NT) tlds[i] = tune[b*TT + i];
  if (tid < 128) hbuf[tid] = 0u;
  for (int idx = tid; idx < 2*KLDS*G4; idx += NT) {
    int row = idx >> 10, p = idx & 1023;
    int gg = row / KLDS, r = row % KLDS;
    Ulds[idx] = Up[(gg*64 + KREG + r)*G4 + p];
  }

  uint4 ureg[KREG];
  {
    const uint32_t* ubase = Up + (size_t)(g*64)*G4 + 4*q;
#pragma unroll
    for (int kk = 0; kk < KREG; kk++) ureg[kk] = *(const uint4*)(ubase + (size_t)kk*G4);
  }
  float4 ctxv = *(const float4*)(ctxW + (size_t)b*G4 + 4*q);
  float cc = 0.f;
  __syncthreads();

  const uint32_t* uldsrow = Ulds + (size_t)(g*KLDS)*G4 + 4*q;
  const uint32_t* hg = hbuf + g*64;       // own group's packed-h slice (uniform)
  bool owner = ((q >> 7) == g);           // wave-uniform
  __half* hh_base = h_hist + (size_t)b*TT*HH + q;
  __half pend = __float2half(0.f);        // h[t-1] awaiting store

  for (int t = 0; t < L; t++) {
    // deferred history store: h[t-1] has the whole dot2 phase to retire
    // before the next vmcnt(0) drain at barrier 1.
    if (owner && t > 0) hh_base[(size_t)(t-1)*HH] = pend;

    int v = tlds[t];
    float4 tw = *(const float4*)(tuneW + (size_t)v*G4 + 4*q);   // issued early

    float a0e = 0.f, a1e = 0.f, a2e = 0.f, a3e = 0.f;
    float a0o = 0.f, a1o = 0.f, a2o = 0.f, a3o = 0.f;
#pragma unroll
    for (int kq = 0; kq < KREG/4; kq++) {
      uint4 h4 = *(const uint4*)(hg + 4*kq);    // uniform b128 -> broadcast
      a0e = fdot2(h4.x, ureg[4*kq+0].x, a0e);
      a1e = fdot2(h4.x, ureg[4*kq+0].y, a1e);
      a2e = fdot2(h4.x, ureg[4*kq+0].z, a2e);
      a3e = fdot2(h4.x, ureg[4*kq+0].w, a3e);
      a0o = fdot2(h4.y, ureg[4*kq+1].x, a0o);
      a1o = fdot2(h4.y, ureg[4*kq+1].y, a1o);
      a2o = fdot2(h4.y, ureg[4*kq+1].z, a2o);
      a3o = fdot2(h4.y, ureg[4*kq+1].w, a3o);
      a0e = fdot2(h4.z, ureg[4*kq+2].x, a0e);
      a1e = fdot2(h4.z, ureg[4*kq+2].y, a1e);
      a2e = fdot2(h4.z, ureg[4*kq+2].z, a2e);
      a3e = fdot2(h4.z, ureg[4*kq+2].w, a3e);
      a0o = fdot2(h4.w, ureg[4*kq+3].x, a0o);
      a1o = fdot2(h4.w, ureg[4*kq+3].y, a1o);
      a2o = fdot2(h4.w, ureg[4*kq+3].z, a2o);
      a3o = fdot2(h4.w, ureg[4*kq+3].w, a3o);
    }
#pragma unroll
    for (int r4 = 0; r4 < KLDS/4; r4++) {
      uint4 h4 = *(const uint4*)(hg + KREG + 4*r4);
      uint4 ua = *(const uint4*)(uldsrow + (size_t)(4*r4+0)*G4);
      uint4 ub = *(const uint4*)(uldsrow + (size_t)(4*r4+1)*G4);
      uint4 uc = *(const uint4*)(uldsrow + (size_t)(4*r4+2)*G4);
      uint4 ud = *(const uint4*)(uldsrow + (size_t)(4*r4+3)*G4);
      a0e = fdot2(h4.x, ua.x, a0e);
      a1e = fdot2(h4.x, ua.y, a1e);
      a2e = fdot2(h4.x, ua.z, a2e);
      a3e = fdot2(h4.x, ua.w, a3e);
      a0o = fdot2(h4.y, ub.x, a0o);
      a1o = fdot2(h4.y, ub.y, a1o);
      a2o = fdot2(h4.y, ub.z, a2o);
      a3o = fdot2(h4.y, ub.w, a3o);
      a0e = fdot2(h4.z, uc.x, a0e);
      a1e = fdot2(h4.z, uc.y, a1e);
      a2e = fdot2(h4.z, uc.z, a2e);
      a3e = fdot2(h4.z, uc.w, a3e);
      a0o = fdot2(h4.w, ud.x, a0o);
      a1o = fdot2(h4.w, ud.y, a1o);
      a2o = fdot2(h4.w, ud.z, a2o);
      a3o = fdot2(h4.w, ud.w, a3o);
    }
    float s0 = a0e + a0o, s1 = a1e + a1o, s2 = a2e + a2o, s3 = a3e + a3o;
    *(float4*)(zpart + g*G4 + 4*q) = make_float4(s0, s1, s2, s3);
    __syncthreads();

    // fully parallel epilogue (redundant across the 2 groups)
    float4 zp = *(const float4*)(zpart + (1-g)*G4 + 4*q);
    float zi = s0 + zp.x + ctxv.x + tw.x;
    float zf = s1 + zp.y + ctxv.y + tw.y;
    float zg = s2 + zp.z + ctxv.z + tw.z;
    float zo = s3 + zp.w + ctxv.w + tw.w;
    float gi = 1.f / (1.f + __expf(-zi));
    float gf = 1.f / (1.f + __expf(-zf));
    float e2 = __expf(2.f*zg);
    float gg = (e2 - 1.f) / (e2 + 1.f);
    float go = 1.f / (1.f + __expf(-zo));
    cc = gf*cc + gi*gg;
    float ec = __expf(2.f*cc);
    float th = (ec - 1.f) / (ec + 1.f);
    float hv = go * th;
    if (owner) {
      __half hhv = __float2half(hv);
      ((__half*)hbuf)[q] = hhv;           // group-internal publish (LDS only)
      pend = hhv;                         // global store deferred to next iter
    }
    __syncthreads();
  }
  if (owner && L > 0) hh_base[(size_t)(L-1)*HH] = pend;
}

// ---------------- output projection ----------------
// out[b,t,:] = h[b,t,:] @ Wd + bd  (t < L), else bd.
// h history lives (f16-packed) in d_out itself; each block stages its A-tile to
// LDS before overwriting exactly those rows -> no race (rows are block-private).

__global__ __launch_bounds__(256) void out_gemm_k(
    const uint32_t* __restrict__ hsrc, const uint32_t* __restrict__ Wdp,
    const float* __restrict__ bd, const int* __restrict__ tlen,
    float* __restrict__ out) {
  __shared__ uint32_t A[64][128];
  int bb = blockIdx.x;
  int b  = bb >> 3, t0 = (bb & 7) << 6;
  int tid = threadIdx.x;
  int L = tlen[b];
  for (int idx = tid; idx < 64*128; idx += 256) {
    int r = idx >> 7, kp = idx & 127;
    int t = t0 + r;
    A[r][kp] = (t < TT) ? hsrc[((size_t)b*TT + t)*128 + kp] : 0u;
  }
  __syncthreads();
  int v = tid & 127, rg = tid >> 7;
  float acc[32];
#pragma unroll
  for (int r = 0; r < 32; r++) acc[r] = 0.f;
  for (int kb = 0; kb < 4; kb++) {
    uint32_t w[32];
#pragma unroll
    for (int q = 0; q < 32; q++) w[q] = Wdp[(kb*32+q)*VV + v];
#pragma unroll
    for (int r = 0; r < 32; r++) {
      const uint32_t* ar = &A[rg*32 + r][kb*32];
#pragma unroll
      for (int q4 = 0; q4 < 8; q4++) {
        uint4 a4 = *(const uint4*)(ar + q4*4);
        acc[r] = fdot2(a4.x, w[4*q4+0], acc[r]);
        acc[r] = fdot2(a4.y, w[4*q4+1], acc[r]);
        acc[r] = fdot2(a4.z, w[4*q4+2], acc[r]);
        acc[r] = fdot2(a4.w, w[4*q4+3], acc[r]);
      }
    }
  }
  float bias = bd[v];
#pragma unroll
  for (int r = 0; r < 32; r++) {
    int t = t0 + rg*32 + r;
    if (t < TT) {
      out[((size_t)b*TT + t)*VV + v] = (t < L) ? (acc[r] + bias) : bias;
    }
  }
}

// ---------------- launch ----------------

extern "C" void kernel_launch(void* const* d_in, const int* in_sizes, int n_in,
                              void* d_out, int out_size, void* d_ws, size_t ws_size,
                              hipStream_t stream) {
  const int*   tune   = (const int*)d_in[0];
  const int*   rhythm = (const int*)d_in[1];
  const int*   meter  = (const int*)d_in[2];
  const int*   keyi   = (const int*)d_in[3];
  const int*   tlen   = (const int*)d_in[4];
  const float* er     = (const float*)d_in[5];
  const float* em     = (const float*)d_in[6];
  const float* ek     = (const float*)d_in[7];
  const float* et     = (const float*)d_in[8];
  const float* W      = (const float*)d_in[9];
  const float* U      = (const float*)d_in[10];
  const float* bias   = (const float*)d_in[11];
  const float* Wd     = (const float*)d_in[12];
  const float* bd     = (const float*)d_in[13];
  (void)in_sizes; (void)n_in; (void)out_size; (void)ws_size;

  char* ws = (char*)d_ws;
  uint32_t* Up    = (uint32_t*)(ws);                                      // 512KB
  float*    ctxW  = (float*)(ws + (512<<10));                             // 1MB
  float*    tuneW = (float*)(ws + (512<<10) + (1024<<10));                // 516KB
  uint32_t* Wdp   = (uint32_t*)(ws + (512<<10) + (1024<<10) + (516<<10)); // 64KB

  hipFuncSetAttribute((const void*)lstm_rec_k,
                      hipFuncAttributeMaxDynamicSharedMemorySize, SMEM_BYTES);

  prep_ctx_k <<<BB,    1024, 0, stream>>>(rhythm, meter, keyi, er, em, ek, W, bias, ctxW);
  prep_tune_k<<<VV+1,  1024, 0, stream>>>(et, W, tuneW);
  prep_U_k   <<<128,   1024, 0, stream>>>(U, Up);
  prep_Wd_k  <<<128,   VV,   0, stream>>>(Wd, Wdp);
  lstm_rec_k <<<BB, NT, SMEM_BYTES, stream>>>(tune, tlen, Up, ctxW, tuneW, (__half*)d_out);
  out_gemm_k <<<BB*8,  256,  0, stream>>>((const uint32_t*)d_out, Wdp, bd, tlen, (float*)d_out);
}